// Round 6
// baseline (39.000 us; speedup 1.0000x reference)
//
#include <hip/hip_runtime.h>

// Perceptual color difference (CIELAB, lightness_weight = 0).
// Inputs: img1, img2 : (B=32, C=3, H=512, W=512) float32, NCHW.
// Output: per-batch mean over HxW of sqrt(da^2 + db^2), 32 floats.
//
// Round 6: same math as round 5 (absmax 0.0). Structural change only:
// 2-stage software-pipelined prefetch, 4 chunks/thread (BPB=64), so every
// compute phase overlaps the next chunk's 6 global_load_dwordx4. Attacks the
// measured latency gap (VALUBusy ~30%, VGPR=24 -> loads were serialized).

typedef float v2f __attribute__((ext_vector_type(2)));
typedef float v4f __attribute__((ext_vector_type(4)));

#define HW (512 * 512)
#define NB 32
#define BPB 64                   // blocks per batch
#define THREADS 256
#define STRIDE (BPB * THREADS)   // 16384 float4; nvec = 65536 = 4*STRIDE

__device__ __forceinline__ v2f v2exp2(v2f x) {
    v2f r;
    r.x = __builtin_amdgcn_exp2f(x.x);
    r.y = __builtin_amdgcn_exp2f(x.y);
    return r;
}
__device__ __forceinline__ v2f v2log2(v2f x) {
    v2f r;
    r.x = __builtin_amdgcn_logf(x.x);
    r.y = __builtin_amdgcn_logf(x.y);
    return r;
}

__device__ __forceinline__ v2f srgb2(v2f c) {
    v2f p = v2exp2(v2log2(c + 0.055f) * 2.4f);
    v2f lo = c * 0.08801236f;
    v2f r;
    r.x = (c.x <= 0.04045f) ? lo.x : p.x;
    r.y = (c.y <= 0.04045f) ? lo.y : p.y;
    return r;
}

__device__ __forceinline__ v2f labf2(v2f x, float A, float B, float thr) {
    v2f g = v2exp2(v2log2(x) * (1.0f / 3.0f));
    v2f lo = x * A + B;
    v2f r;
    r.x = (x.x > thr) ? g.x : lo.x;
    r.y = (x.y > thr) ? g.y : lo.y;
    return r;
}

__device__ __forceinline__ void pipe(v2f r, v2f g, v2f u, v2f& apk, v2f& bpk) {
    v2f lr = srgb2(r), lg = srgb2(g), lb = srgb2(u);
    v2f x = lr * 0.3627198f + lg * 0.3144573f + lb * 0.1586792f;
    v2f y = lr * 0.1870275f + lg * 0.6289146f + lb * 0.0634717f;
    v2f z = lr * 0.0170025f + lg * 0.1048191f + lb * 0.8357104f;
    v2f sx = labf2(x, 8.0551810f, 0.13561340f, 0.008417790f);
    v2f sy = labf2(y, 7.7870370f, 0.13793103f, 0.008856452f);
    v2f sz = labf2(z, 7.3575050f, 0.14189940f, 0.009643159f);
    apk = sx * 508.54415f - sy * 500.0f;
    bpk = sy * 200.0f - sz * 194.40678f;
}

__device__ __forceinline__ float comp_chunk(v4f r1, v4f g1, v4f u1,
                                            v4f r2, v4f g2, v4f u2) {
    float s = 0.0f;
#pragma unroll
    for (int h = 0; h < 2; ++h) {
        v2f R1 = h ? __builtin_shufflevector(r1, r1, 2, 3) : __builtin_shufflevector(r1, r1, 0, 1);
        v2f G1 = h ? __builtin_shufflevector(g1, g1, 2, 3) : __builtin_shufflevector(g1, g1, 0, 1);
        v2f U1 = h ? __builtin_shufflevector(u1, u1, 2, 3) : __builtin_shufflevector(u1, u1, 0, 1);
        v2f R2 = h ? __builtin_shufflevector(r2, r2, 2, 3) : __builtin_shufflevector(r2, r2, 0, 1);
        v2f G2 = h ? __builtin_shufflevector(g2, g2, 2, 3) : __builtin_shufflevector(g2, g2, 0, 1);
        v2f U2 = h ? __builtin_shufflevector(u2, u2, 2, 3) : __builtin_shufflevector(u2, u2, 0, 1);
        v2f a1, b1, a2, b2;
        pipe(R1, G1, U1, a1, b1);
        pipe(R2, G2, U2, a2, b2);
        v2f da = a1 - a2;
        v2f db = b1 - b2;
        v2f e = da * da + db * db;
        s += __builtin_amdgcn_sqrtf(e.x) + __builtin_amdgcn_sqrtf(e.y);
    }
    return s;
}

#define LOADSET(P1, P2, R1, G1, U1, R2, G2, U2, IDX) \
    R1 = P1[(IDX)];            G1 = P1[(IDX) + coff]; U1 = P1[(IDX) + 2 * coff]; \
    R2 = P2[(IDX)];            G2 = P2[(IDX) + coff]; U2 = P2[(IDX) + 2 * coff];

__global__ __launch_bounds__(THREADS) void cd_partial(
    const float* __restrict__ img1, const float* __restrict__ img2,
    float* __restrict__ ws) {
    const int b = blockIdx.y;
    const size_t base = (size_t)b * 3 * HW;
    const v4f* __restrict__ p1 = (const v4f*)(img1 + base);
    const v4f* __restrict__ p2 = (const v4f*)(img2 + base);
    const int coff = HW / 4;
    const int i0 = blockIdx.x * THREADS + threadIdx.x;

    v4f ar1, ag1, au1, ar2, ag2, au2;   // stage A
    v4f br1, bg1, bu1, br2, bg2, bu2;   // stage B

    // prologue: chunks 0 and 1 in flight together
    LOADSET(p1, p2, ar1, ag1, au1, ar2, ag2, au2, i0);
    LOADSET(p1, p2, br1, bg1, bu1, br2, bg2, bu2, i0 + STRIDE);

    float sum = comp_chunk(ar1, ag1, au1, ar2, ag2, au2);        // chunk 0
    LOADSET(p1, p2, ar1, ag1, au1, ar2, ag2, au2, i0 + 2 * STRIDE);
    sum += comp_chunk(br1, bg1, bu1, br2, bg2, bu2);             // chunk 1
    LOADSET(p1, p2, br1, bg1, bu1, br2, bg2, bu2, i0 + 3 * STRIDE);
    sum += comp_chunk(ar1, ag1, au1, ar2, ag2, au2);             // chunk 2
    sum += comp_chunk(br1, bg1, bu1, br2, bg2, bu2);             // chunk 3

    // wave64 reduce
#pragma unroll
    for (int off = 32; off > 0; off >>= 1) sum += __shfl_down(sum, off);

    __shared__ float ssum[THREADS / 64];
    const int lane = threadIdx.x & 63;
    const int wid = threadIdx.x >> 6;
    if (lane == 0) ssum[wid] = sum;
    __syncthreads();
    if (threadIdx.x == 0) {
        float s = 0.0f;
#pragma unroll
        for (int w = 0; w < THREADS / 64; ++w) s += ssum[w];
        ws[(size_t)b * BPB + blockIdx.x] = s;
    }
}

// Stage 2: reduce BPB partials per batch, divide by HW.
__global__ __launch_bounds__(64) void cd_final(
    const float* __restrict__ ws, float* __restrict__ out) {
    const int b = blockIdx.x;
    float s = ws[(size_t)b * BPB + threadIdx.x];
#pragma unroll
    for (int off = 32; off > 0; off >>= 1) s += __shfl_down(s, off);
    if (threadIdx.x == 0) out[b] = s * (1.0f / (float)HW);
}

extern "C" void kernel_launch(void* const* d_in, const int* in_sizes, int n_in,
                              void* d_out, int out_size, void* d_ws, size_t ws_size,
                              hipStream_t stream) {
    const float* img1 = (const float*)d_in[0];
    const float* img2 = (const float*)d_in[1];
    float* out = (float*)d_out;
    float* ws = (float*)d_ws;   // NB * BPB * 4 = 8 KB

    dim3 grid1(BPB, NB);
    cd_partial<<<grid1, THREADS, 0, stream>>>(img1, img2, ws);
    cd_final<<<NB, 64, 0, stream>>>(ws, out);
}